// Round 2
// baseline (3592.762 us; speedup 1.0000x reference)
//
#include <hip/hip_runtime.h>
#include <stdint.h>

#define B_N 8192
#define D_N 256
#define K_N 65536
#define EPS_ 1e-7f

// fused GEMM tile config
#define TM 128
#define TN 128
#define DK 32
#define LDT 132  // padded leading dim (floats) to break bank-conflict strides

// monotone float->uint mapping; pack value in high 32, ~idx in low 32 so that
// u64 max == (max value, then smallest index) — matches numpy argmax tie-break.
__device__ __forceinline__ unsigned long long pack_key(float v, uint32_t k) {
    uint32_t u = __float_as_uint(v);
    u = (u & 0x80000000u) ? ~u : (u | 0x80000000u);
    return ((unsigned long long)u << 32) | (unsigned long long)(~k);
}

// cn[k] = ||W[:,k]||  (coalesced along k); also zero-init the packed argmax array.
__global__ void colnorm_init_kernel(const float* __restrict__ W, float* __restrict__ cn,
                                    unsigned long long* __restrict__ packed) {
    int k = blockIdx.x * blockDim.x + threadIdx.x;
    float s = 0.f;
#pragma unroll 8
    for (int d = 0; d < D_N; ++d) {
        float w = W[(size_t)d * K_N + k];
        s = fmaf(w, w, s);
    }
    cn[k] = sqrtf(s);
    if (k < B_N) packed[k] = 0ull;  // any real key beats 0
}

// rn[b] = ||targ[b]||, one wave per row (4 rows per 256-thread block)
__global__ void rownorm_kernel(const float* __restrict__ T, float* __restrict__ rn) {
    int row = blockIdx.x * 4 + (threadIdx.x >> 6);
    int lane = threadIdx.x & 63;
    float4 v = reinterpret_cast<const float4*>(T + (size_t)row * D_N)[lane];
    float s = v.x * v.x + v.y * v.y + v.z * v.z + v.w * v.w;
#pragma unroll
    for (int off = 32; off > 0; off >>= 1) s += __shfl_down(s, off);
    if (lane == 0) rn[row] = sqrtf(s);
}

// Fused f32 GEMM + cosine scale + per-row argmax (block-local reduce + global atomicMax).
// Tile: 128 rows x 128 cols, 256 threads (16x16), 8x8 micro-tile, D chunked by 32 in LDS.
__launch_bounds__(256) __global__
void fused_sim_argmax_kernel(const float* __restrict__ T, const float* __restrict__ W,
                             const float* __restrict__ rn, const float* __restrict__ cn,
                             unsigned long long* __restrict__ packed) {
    __shared__ __align__(16) float As[DK][LDT];  // As[d][r] = T[r0+r][d0+d] (transposed store)
    __shared__ __align__(16) float Ws[DK][LDT];  // Ws[d][c] = W[d0+d][c0+c]

    const int tid = threadIdx.x;
    const int tx = tid & 15;   // col group (lane bits 0-3 -> shfl reduce works in-wave)
    const int ty = tid >> 4;   // row group
    const int r0 = blockIdx.y * TM;
    const int c0 = blockIdx.x * TN;

    float acc[8][8] = {};

    for (int d0 = 0; d0 < D_N; d0 += DK) {
        // stage A chunk: 128 rows x 32 d, transposed into As[d][r]
#pragma unroll
        for (int t = 0; t < 4; ++t) {
            int fidx = tid + t * 256;          // 0..1023 float4 slots
            int r = fidx >> 3;                 // 8 float4 per row
            int dq = fidx & 7;
            float4 v = *reinterpret_cast<const float4*>(T + (size_t)(r0 + r) * D_N + d0 + dq * 4);
            As[dq * 4 + 0][r] = v.x;
            As[dq * 4 + 1][r] = v.y;
            As[dq * 4 + 2][r] = v.z;
            As[dq * 4 + 3][r] = v.w;
        }
        // stage W chunk: 32 d x 128 cols, natural layout
#pragma unroll
        for (int t = 0; t < 4; ++t) {
            int fidx = tid + t * 256;
            int dd = fidx >> 5;                // 32 float4 per d-row
            int c4 = fidx & 31;
            float4 v = *reinterpret_cast<const float4*>(W + (size_t)(d0 + dd) * K_N + c0 + c4 * 4);
            *reinterpret_cast<float4*>(&Ws[dd][c4 * 4]) = v;
        }
        __syncthreads();

#pragma unroll 8
        for (int dd = 0; dd < DK; ++dd) {
            float a[8], w[8];
            *reinterpret_cast<float4*>(&a[0]) = *reinterpret_cast<const float4*>(&As[dd][ty * 8]);
            *reinterpret_cast<float4*>(&a[4]) = *reinterpret_cast<const float4*>(&As[dd][ty * 8 + 4]);
            *reinterpret_cast<float4*>(&w[0]) = *reinterpret_cast<const float4*>(&Ws[dd][tx * 8]);
            *reinterpret_cast<float4*>(&w[4]) = *reinterpret_cast<const float4*>(&Ws[dd][tx * 8 + 4]);
#pragma unroll
            for (int i = 0; i < 8; ++i)
#pragma unroll
                for (int j = 0; j < 8; ++j)
                    acc[i][j] = fmaf(a[i], w[j], acc[i][j]);
        }
        __syncthreads();
    }

    // epilogue: cosine scale + argmax
    float rns[8], cns[8];
#pragma unroll
    for (int i = 0; i < 8; ++i) rns[i] = rn[r0 + ty * 8 + i];
#pragma unroll
    for (int j = 0; j < 8; ++j) cns[j] = cn[c0 + tx * 8 + j];

#pragma unroll
    for (int i = 0; i < 8; ++i) {
        unsigned long long key = 0ull;
#pragma unroll
        for (int j = 0; j < 8; ++j) {
            float v = acc[i][j] / (rns[i] * cns[j] + EPS_);
            unsigned long long cand = pack_key(v, (uint32_t)(c0 + tx * 8 + j));
            key = cand > key ? cand : key;
        }
        // reduce across the 16 threads (tx) sharing this row — all within one wave
#pragma unroll
        for (int m = 1; m <= 8; m <<= 1) {
            uint32_t lo = (uint32_t)key;
            uint32_t hi = (uint32_t)(key >> 32);
            lo = __shfl_xor(lo, m);
            hi = __shfl_xor(hi, m);
            unsigned long long o = ((unsigned long long)hi << 32) | (unsigned long long)lo;
            key = o > key ? o : key;
        }
        if (tx == 0) atomicMax(&packed[r0 + ty * 8 + i], key);
    }
}

// out[b][:] = W[:, idx[b]]
__global__ void gather_kernel(const float* __restrict__ W,
                              const unsigned long long* __restrict__ packed,
                              float* __restrict__ out) {
    int b = blockIdx.x;
    int d = threadIdx.x;
    uint32_t idx = ~(uint32_t)(packed[b]);  // recover k from ~k
    out[(size_t)b * D_N + d] = W[(size_t)d * K_N + idx];
}

extern "C" void kernel_launch(void* const* d_in, const int* in_sizes, int n_in,
                              void* d_out, int out_size, void* d_ws, size_t ws_size,
                              hipStream_t stream) {
    const float* T = (const float*)d_in[0];   // [B, D]
    const float* W = (const float*)d_in[1];   // [D, K]
    float* out = (float*)d_out;               // [B, D]

    // workspace layout: cn[K] f32 | rn[B] f32 | packed[B] u64   (total 352 KB)
    float* cn = (float*)d_ws;
    float* rn = cn + K_N;
    unsigned long long* packed = (unsigned long long*)(rn + B_N);

    colnorm_init_kernel<<<K_N / 256, 256, 0, stream>>>(W, cn, packed);
    rownorm_kernel<<<B_N / 4, 256, 0, stream>>>(T, rn);

    dim3 grid(K_N / TN, B_N / TM);  // (512, 64)
    fused_sim_argmax_kernel<<<grid, 256, 0, stream>>>(T, W, rn, cn, packed);

    gather_kernel<<<B_N, 256, 0, stream>>>(W, packed, out);
}

// Round 4
// 2237.782 us; speedup vs baseline: 1.6055x; 1.6055x over previous
//
#include <hip/hip_runtime.h>
#include <stdint.h>

#define B_N 8192
#define D_N 256
#define K_N 65536
#define EPS_ 1e-7f

#define T_SCALE 256.0f
#define W_SCALE 1024.0f
#define INV_SCALE (1.0f / 262144.0f)   // 1 / (256*1024), exact power of 2

typedef _Float16 half8 __attribute__((ext_vector_type(8)));
typedef _Float16 half4 __attribute__((ext_vector_type(4)));
typedef float f32x4 __attribute__((ext_vector_type(4)));

// monotone float->uint mapping; pack value in high 32, ~idx in low 32 so that
// u64 max == (max value, then smallest index) — matches numpy argmax tie-break.
__device__ __forceinline__ unsigned long long pack_key(float v, uint32_t k) {
    uint32_t u = __float_as_uint(v);
    u = (u & 0x80000000u) ? ~u : (u | 0x80000000u);
    return ((unsigned long long)u << 32) | (unsigned long long)(~k);
}

// ---------- shared prep kernels (operate on ORIGINAL data) ----------

__global__ void colnorm_init_kernel(const float* __restrict__ W, float* __restrict__ cn,
                                    unsigned long long* __restrict__ packed) {
    int k = blockIdx.x * blockDim.x + threadIdx.x;
    float s = 0.f;
#pragma unroll 8
    for (int d = 0; d < D_N; ++d) {
        float w = W[(size_t)d * K_N + k];
        s = fmaf(w, w, s);
    }
    cn[k] = sqrtf(s);
    if (k < B_N) packed[k] = 0ull;
}

__global__ void rownorm_kernel(const float* __restrict__ T, float* __restrict__ rn) {
    int row = blockIdx.x * 4 + (threadIdx.x >> 6);
    int lane = threadIdx.x & 63;
    float4 v = reinterpret_cast<const float4*>(T + (size_t)row * D_N)[lane];
    float s = v.x * v.x + v.y * v.y + v.z * v.z + v.w * v.w;
#pragma unroll
    for (int off = 32; off > 0; off >>= 1) s += __shfl_down(s, off);
    if (lane == 0) rn[row] = sqrtf(s);
}

__global__ void gather_kernel(const float* __restrict__ W,
                              const unsigned long long* __restrict__ packed,
                              float* __restrict__ out) {
    int b = blockIdx.x;
    int d = threadIdx.x;
    uint32_t idx = ~(uint32_t)(packed[b]);
    out[(size_t)b * D_N + d] = W[(size_t)d * K_N + idx];
}

// ---------- fp16 split conversion ----------

// T [8192][256] f32 -> Ah, Al [8192][256] fp16 (scaled by 256)
__global__ void convT_kernel(const float* __restrict__ T,
                             _Float16* __restrict__ Ah, _Float16* __restrict__ Al) {
    int i = blockIdx.x * 256 + threadIdx.x;       // float4 index
    float4 v = reinterpret_cast<const float4*>(T)[i];
    float x[4] = {v.x, v.y, v.z, v.w};
    half4 hv, lv;
#pragma unroll
    for (int j = 0; j < 4; ++j) {
        float s = x[j] * T_SCALE;
        _Float16 h = (_Float16)s;
        hv[j] = h;
        lv[j] = (_Float16)(s - (float)h);
    }
    reinterpret_cast<half4*>(Ah)[i] = hv;
    reinterpret_cast<half4*>(Al)[i] = lv;
}

// W [256][65536] f32 -> Bh, Bl [65536][256] fp16 TRANSPOSED (scaled by 1024)
// 64(k) x 64(d) tile via LDS
__global__ void convW_kernel(const float* __restrict__ W,
                             _Float16* __restrict__ Bh, _Float16* __restrict__ Bl) {
    __shared__ _Float16 Lh[64][66], Ll[64][66];   // [d_local][k_local], padded
    int k0 = blockIdx.x * 64, d0 = blockIdx.y * 64;
    int t = threadIdx.x;
#pragma unroll
    for (int i = 0; i < 16; ++i) {
        int flat = i * 256 + t;                   // 0..4095
        int dl = flat >> 6, kl = flat & 63;       // lanes -> consecutive k (coalesced)
        float x = W[(size_t)(d0 + dl) * K_N + k0 + kl] * W_SCALE;
        _Float16 h = (_Float16)x;
        Lh[dl][kl] = h;
        Ll[dl][kl] = (_Float16)(x - (float)h);
    }
    __syncthreads();
#pragma unroll
    for (int j = 0; j < 2; ++j) {
        int flat = j * 256 + t;                   // 0..511
        int kr = flat >> 3, seg = flat & 7;
        half8 vh, vl;
#pragma unroll
        for (int e = 0; e < 8; ++e) {
            vh[e] = Lh[seg * 8 + e][kr];
            vl[e] = Ll[seg * 8 + e][kr];
        }
        *reinterpret_cast<half8*>(Bh + (size_t)(k0 + kr) * D_N + d0 + seg * 8) = vh;
        *reinterpret_cast<half8*>(Bl + (size_t)(k0 + kr) * D_N + d0 + seg * 8) = vl;
    }
}

// ---------- fused MFMA GEMM + argmax (m97 structure: 128^2 tile, BK=32, 2-barrier) ----------

__device__ __forceinline__ void gload_lds16(const void* g, void* l) {
    __builtin_amdgcn_global_load_lds((const __attribute__((address_space(1))) unsigned int*)g,
                                     (__attribute__((address_space(3))) unsigned int*)l, 16, 0, 0);
}

__launch_bounds__(256) __global__
void fused_mfma_kernel(const _Float16* __restrict__ Ah, const _Float16* __restrict__ Al,
                       const _Float16* __restrict__ Bh, const _Float16* __restrict__ Bl,
                       const float* __restrict__ rn, const float* __restrict__ cn,
                       unsigned long long* __restrict__ packed) {
    __shared__ _Float16 As[128][32];   // [row][k]  8KB
    __shared__ _Float16 Bs[128][32];   // [col][k]  8KB

    const int tid = threadIdx.x;
    const int lane = tid & 63, wid = tid >> 6;
    const int wr = wid >> 1, wc = wid & 1;           // wave -> 64x64 quadrant
    const int r0 = blockIdx.y * 128, c0 = blockIdx.x * 128;

    f32x4 acc[4][4];
#pragma unroll
    for (int i = 0; i < 4; ++i)
#pragma unroll
        for (int j = 0; j < 4; ++j) acc[i][j] = (f32x4){0.f, 0.f, 0.f, 0.f};

    const int lrow = lane >> 2, lcol = (lane & 3) * 8;   // staging: lane -> 16B slot
    const int frow = lane & 15, fk = (lane >> 4) * 8;    // MFMA fragment mapping

    // K_eff = 768: chunks 0-7 = Ah*Bh, 8-15 = Ah*Bl, 16-23 = Al*Bh (drop l*l ~ 2^-24)
    for (int ch = 0; ch < 24; ++ch) {
        const int term = ch >> 3;
        const int d0 = (ch & 7) << 5;
        const _Float16* Asrc = (term < 2) ? Ah : Al;
        const _Float16* Bsrc = (term == 1) ? Bl : Bh;

        const _Float16* ga = Asrc + (size_t)(r0 + wid * 16 + lrow) * D_N + d0 + lcol;
        gload_lds16(ga,            &As[wid * 16][0]);
        gload_lds16(ga + 64 * D_N, &As[64 + wid * 16][0]);
        const _Float16* gb = Bsrc + (size_t)(c0 + wid * 16 + lrow) * D_N + d0 + lcol;
        gload_lds16(gb,            &Bs[wid * 16][0]);
        gload_lds16(gb + 64 * D_N, &Bs[64 + wid * 16][0]);

        __syncthreads();   // compiler emits vmcnt(0) drain before barrier

        half8 a[4], b[4];
#pragma unroll
        for (int mi = 0; mi < 4; ++mi)
            a[mi] = *reinterpret_cast<const half8*>(&As[wr * 64 + mi * 16 + frow][fk]);
#pragma unroll
        for (int ni = 0; ni < 4; ++ni)
            b[ni] = *reinterpret_cast<const half8*>(&Bs[wc * 64 + ni * 16 + frow][fk]);
#pragma unroll
        for (int mi = 0; mi < 4; ++mi)
#pragma unroll
            for (int ni = 0; ni < 4; ++ni)
                acc[mi][ni] = __builtin_amdgcn_mfma_f32_16x16x32_f16(a[mi], b[ni], acc[mi][ni], 0, 0, 0);

        __syncthreads();
    }

    // epilogue: C/D layout col=lane&15, row=(lane>>4)*4+reg (m89-verified, dtype-independent)
    const int q = lane >> 4;
    const int cl = lane & 15;
    float cns[4];
#pragma unroll
    for (int ni = 0; ni < 4; ++ni) cns[ni] = cn[c0 + wc * 64 + ni * 16 + cl];

#pragma unroll
    for (int mi = 0; mi < 4; ++mi) {
#pragma unroll
        for (int reg = 0; reg < 4; ++reg) {
            const int row = r0 + wr * 64 + mi * 16 + q * 4 + reg;
            const float rv = rn[row];
            unsigned long long key = 0ull;
#pragma unroll
            for (int ni = 0; ni < 4; ++ni) {
                float v = acc[mi][ni][reg] * INV_SCALE / (rv * cns[ni] + EPS_);
                unsigned long long cand = pack_key(v, (uint32_t)(c0 + wc * 64 + ni * 16 + cl));
                key = cand > key ? cand : key;
            }
            // reduce across the 16 lanes sharing q (they hold the same rows, different cols)
#pragma unroll
            for (int m = 1; m <= 8; m <<= 1) {
                uint32_t lo = (uint32_t)key, hi = (uint32_t)(key >> 32);
                lo = __shfl_xor(lo, m);
                hi = __shfl_xor(hi, m);
                unsigned long long o = ((unsigned long long)hi << 32) | (unsigned long long)lo;
                key = o > key ? o : key;
            }
            if (cl == 0) atomicMax(&packed[row], key);
        }
    }
}

// ---------- f32 fallback (round-2 verified path, used only if ws too small) ----------

#define TM 128
#define TN 128
#define DK 32
#define LDT 132

__launch_bounds__(256) __global__
void fused_sim_argmax_kernel(const float* __restrict__ T, const float* __restrict__ W,
                             const float* __restrict__ rn, const float* __restrict__ cn,
                             unsigned long long* __restrict__ packed) {
    __shared__ __align__(16) float As[DK][LDT];
    __shared__ __align__(16) float Ws[DK][LDT];
    const int tid = threadIdx.x;
    const int tx = tid & 15, ty = tid >> 4;
    const int r0 = blockIdx.y * TM, c0 = blockIdx.x * TN;
    float acc[8][8] = {};
    for (int d0 = 0; d0 < D_N; d0 += DK) {
#pragma unroll
        for (int t = 0; t < 4; ++t) {
            int fidx = tid + t * 256;
            int r = fidx >> 3, dq = fidx & 7;
            float4 v = *reinterpret_cast<const float4*>(T + (size_t)(r0 + r) * D_N + d0 + dq * 4);
            As[dq * 4 + 0][r] = v.x; As[dq * 4 + 1][r] = v.y;
            As[dq * 4 + 2][r] = v.z; As[dq * 4 + 3][r] = v.w;
        }
#pragma unroll
        for (int t = 0; t < 4; ++t) {
            int fidx = tid + t * 256;
            int dd = fidx >> 5, c4 = fidx & 31;
            float4 v = *reinterpret_cast<const float4*>(W + (size_t)(d0 + dd) * K_N + c0 + c4 * 4);
            *reinterpret_cast<float4*>(&Ws[dd][c4 * 4]) = v;
        }
        __syncthreads();
#pragma unroll 8
        for (int dd = 0; dd < DK; ++dd) {
            float a[8], w[8];
            *reinterpret_cast<float4*>(&a[0]) = *reinterpret_cast<const float4*>(&As[dd][ty * 8]);
            *reinterpret_cast<float4*>(&a[4]) = *reinterpret_cast<const float4*>(&As[dd][ty * 8 + 4]);
            *reinterpret_cast<float4*>(&w[0]) = *reinterpret_cast<const float4*>(&Ws[dd][tx * 8]);
            *reinterpret_cast<float4*>(&w[4]) = *reinterpret_cast<const float4*>(&Ws[dd][tx * 8 + 4]);
#pragma unroll
            for (int i = 0; i < 8; ++i)
#pragma unroll
                for (int j = 0; j < 8; ++j) acc[i][j] = fmaf(a[i], w[j], acc[i][j]);
        }
        __syncthreads();
    }
    float rns[8], cns[8];
#pragma unroll
    for (int i = 0; i < 8; ++i) rns[i] = rn[r0 + ty * 8 + i];
#pragma unroll
    for (int j = 0; j < 8; ++j) cns[j] = cn[c0 + tx * 8 + j];
#pragma unroll
    for (int i = 0; i < 8; ++i) {
        unsigned long long key = 0ull;
#pragma unroll
        for (int j = 0; j < 8; ++j) {
            float v = acc[i][j] / (rns[i] * cns[j] + EPS_);
            unsigned long long cand = pack_key(v, (uint32_t)(c0 + tx * 8 + j));
            key = cand > key ? cand : key;
        }
#pragma unroll
        for (int m = 1; m <= 8; m <<= 1) {
            uint32_t lo = (uint32_t)key, hi = (uint32_t)(key >> 32);
            lo = __shfl_xor(lo, m); hi = __shfl_xor(hi, m);
            unsigned long long o = ((unsigned long long)hi << 32) | (unsigned long long)lo;
            key = o > key ? o : key;
        }
        if (tx == 0) atomicMax(&packed[r0 + ty * 8 + i], key);
    }
}

// ---------- launch ----------

extern "C" void kernel_launch(void* const* d_in, const int* in_sizes, int n_in,
                              void* d_out, int out_size, void* d_ws, size_t ws_size,
                              hipStream_t stream) {
    const float* T = (const float*)d_in[0];   // [B, D]
    const float* W = (const float*)d_in[1];   // [D, K]
    float* out = (float*)d_out;

    // ws layout (fp16 path):
    //   Bh [K][D] fp16   33,554,432 B
    //   Bl [K][D] fp16   33,554,432 B
    //   Ah [B][D] fp16    4,194,304 B
    //   Al [B][D] fp16    4,194,304 B
    //   cn [K] f32          262,144 B
    //   rn [B] f32           32,768 B
    //   packed [B] u64       65,536 B
    const size_t BH_OFF = 0;
    const size_t BL_OFF = BH_OFF + (size_t)K_N * D_N * 2;
    const size_t AH_OFF = BL_OFF + (size_t)K_N * D_N * 2;
    const size_t AL_OFF = AH_OFF + (size_t)B_N * D_N * 2;
    const size_t CN_OFF = AL_OFF + (size_t)B_N * D_N * 2;
    const size_t RN_OFF = CN_OFF + (size_t)K_N * 4;
    const size_t PK_OFF = RN_OFF + (size_t)B_N * 4;
    const size_t NEED = PK_OFF + (size_t)B_N * 8;

    char* ws = (char*)d_ws;

    if (ws_size >= NEED) {
        _Float16* Bh = (_Float16*)(ws + BH_OFF);
        _Float16* Bl = (_Float16*)(ws + BL_OFF);
        _Float16* Ah = (_Float16*)(ws + AH_OFF);
        _Float16* Al = (_Float16*)(ws + AL_OFF);
        float* cn = (float*)(ws + CN_OFF);
        float* rn = (float*)(ws + RN_OFF);
        unsigned long long* packed = (unsigned long long*)(ws + PK_OFF);

        colnorm_init_kernel<<<K_N / 256, 256, 0, stream>>>(W, cn, packed);
        rownorm_kernel<<<B_N / 4, 256, 0, stream>>>(T, rn);
        convT_kernel<<<B_N * D_N / 4 / 256, 256, 0, stream>>>(T, Ah, Al);
        dim3 gw(K_N / 64, D_N / 64);
        convW_kernel<<<gw, 256, 0, stream>>>(W, Bh, Bl);

        dim3 grid(K_N / 128, B_N / 128);   // (512, 64)
        fused_mfma_kernel<<<grid, 256, 0, stream>>>(Ah, Al, Bh, Bl, rn, cn, packed);

        gather_kernel<<<B_N, 256, 0, stream>>>(W, packed, out);
    } else {
        // f32 fallback (round-2 verified)
        float* cn = (float*)ws;
        float* rn = cn + K_N;
        unsigned long long* packed = (unsigned long long*)(rn + B_N);
        colnorm_init_kernel<<<K_N / 256, 256, 0, stream>>>(W, cn, packed);
        rownorm_kernel<<<B_N / 4, 256, 0, stream>>>(T, rn);
        dim3 grid(K_N / TN, B_N / TM);
        fused_sim_argmax_kernel<<<grid, 256, 0, stream>>>(T, W, rn, cn, packed);
        gather_kernel<<<B_N, 256, 0, stream>>>(W, packed, out);
    }
}

// Round 5
// 1543.792 us; speedup vs baseline: 2.3272x; 1.4495x over previous
//
#include <hip/hip_runtime.h>
#include <stdint.h>

#define B_N 8192
#define D_N 256
#define K_N 65536
#define EPS_ 1e-7f

#define T_SCALE 256.0f
#define W_SCALE 1024.0f
#define INV_SCALE (1.0f / 262144.0f)   // 1 / (256*1024), exact power of 2

typedef _Float16 half8 __attribute__((ext_vector_type(8)));
typedef _Float16 half4 __attribute__((ext_vector_type(4)));
typedef float f32x4 __attribute__((ext_vector_type(4)));

// monotone float->uint mapping; pack value in high 32, ~idx in low 32 so that
// u64 max == (max value, then smallest index) — matches numpy argmax tie-break.
__device__ __forceinline__ unsigned long long pack_key(float v, uint32_t k) {
    uint32_t u = __float_as_uint(v);
    u = (u & 0x80000000u) ? ~u : (u | 0x80000000u);
    return ((unsigned long long)u << 32) | (unsigned long long)(~k);
}

// ---------- shared prep kernels (operate on ORIGINAL data) ----------

__global__ void colnorm_init_kernel(const float* __restrict__ W, float* __restrict__ cn,
                                    unsigned long long* __restrict__ packed) {
    int k = blockIdx.x * blockDim.x + threadIdx.x;
    float s = 0.f;
#pragma unroll 8
    for (int d = 0; d < D_N; ++d) {
        float w = W[(size_t)d * K_N + k];
        s = fmaf(w, w, s);
    }
    cn[k] = sqrtf(s);
    if (k < B_N) packed[k] = 0ull;
}

__global__ void rownorm_kernel(const float* __restrict__ T, float* __restrict__ rn) {
    int row = blockIdx.x * 4 + (threadIdx.x >> 6);
    int lane = threadIdx.x & 63;
    float4 v = reinterpret_cast<const float4*>(T + (size_t)row * D_N)[lane];
    float s = v.x * v.x + v.y * v.y + v.z * v.z + v.w * v.w;
#pragma unroll
    for (int off = 32; off > 0; off >>= 1) s += __shfl_down(s, off);
    if (lane == 0) rn[row] = sqrtf(s);
}

__global__ void gather_kernel(const float* __restrict__ W,
                              const unsigned long long* __restrict__ packed,
                              float* __restrict__ out) {
    int b = blockIdx.x;
    int d = threadIdx.x;
    uint32_t idx = ~(uint32_t)(packed[b]);
    out[(size_t)b * D_N + d] = W[(size_t)d * K_N + idx];
}

// ---------- fp16 split conversion ----------

// T [8192][256] f32 -> Ah, Al [8192][256] fp16 (scaled by 256)
__global__ void convT_kernel(const float* __restrict__ T,
                             _Float16* __restrict__ Ah, _Float16* __restrict__ Al) {
    int i = blockIdx.x * 256 + threadIdx.x;       // float4 index
    float4 v = reinterpret_cast<const float4*>(T)[i];
    float x[4] = {v.x, v.y, v.z, v.w};
    half4 hv, lv;
#pragma unroll
    for (int j = 0; j < 4; ++j) {
        float s = x[j] * T_SCALE;
        _Float16 h = (_Float16)s;
        hv[j] = h;
        lv[j] = (_Float16)(s - (float)h);
    }
    reinterpret_cast<half4*>(Ah)[i] = hv;
    reinterpret_cast<half4*>(Al)[i] = lv;
}

// W [256][65536] f32 -> Bh, Bl [65536][256] fp16 TRANSPOSED (scaled by 1024)
// 64(k) x 64(d) tile via LDS
__global__ void convW_kernel(const float* __restrict__ W,
                             _Float16* __restrict__ Bh, _Float16* __restrict__ Bl) {
    __shared__ _Float16 Lh[64][66], Ll[64][66];   // [d_local][k_local], padded
    int k0 = blockIdx.x * 64, d0 = blockIdx.y * 64;
    int t = threadIdx.x;
#pragma unroll
    for (int i = 0; i < 16; ++i) {
        int flat = i * 256 + t;                   // 0..4095
        int dl = flat >> 6, kl = flat & 63;       // lanes -> consecutive k (coalesced)
        float x = W[(size_t)(d0 + dl) * K_N + k0 + kl] * W_SCALE;
        _Float16 h = (_Float16)x;
        Lh[dl][kl] = h;
        Ll[dl][kl] = (_Float16)(x - (float)h);
    }
    __syncthreads();
#pragma unroll
    for (int j = 0; j < 2; ++j) {
        int flat = j * 256 + t;                   // 0..511
        int kr = flat >> 3, seg = flat & 7;
        half8 vh, vl;
#pragma unroll
        for (int e = 0; e < 8; ++e) {
            vh[e] = Lh[seg * 8 + e][kr];
            vl[e] = Ll[seg * 8 + e][kr];
        }
        *reinterpret_cast<half8*>(Bh + (size_t)(k0 + kr) * D_N + d0 + seg * 8) = vh;
        *reinterpret_cast<half8*>(Bl + (size_t)(k0 + kr) * D_N + d0 + seg * 8) = vl;
    }
}

// ---------- fused MFMA GEMM + argmax ----------
// 128^2 tile, BK=32, T3 2-phase double-buffered pipeline (m248v2-verified recipe),
// XCD-panel swizzle: each XCD owns 64 contiguous column-panels (B panel fetched
// by exactly one XCD's L2; A cycles through L3).

__device__ __forceinline__ void gload_lds16(const void* g, void* l) {
    __builtin_amdgcn_global_load_lds((const __attribute__((address_space(1))) unsigned int*)g,
                                     (__attribute__((address_space(3))) unsigned int*)l, 16, 0, 0);
}

#define NCHUNK 24

__launch_bounds__(256) __global__
void fused_mfma_kernel(const _Float16* __restrict__ Ah, const _Float16* __restrict__ Al,
                       const _Float16* __restrict__ Bh, const _Float16* __restrict__ Bl,
                       const float* __restrict__ rn, const float* __restrict__ cn,
                       unsigned long long* __restrict__ packed) {
    __shared__ _Float16 As[2][128][32];   // double-buffered, 16 KB
    __shared__ _Float16 Bs[2][128][32];   // double-buffered, 16 KB

    const int tid = threadIdx.x;
    const int lane = tid & 63, wid = tid >> 6;
    const int wr = wid >> 1, wc = wid & 1;           // wave -> 64x64 quadrant

    // bijective XCD swizzle (m204): 32768 blocks, 8 XCDs, 4096 blocks/XCD.
    // XCD i owns column-panels [i*64, (i+1)*64); within a panel, row-tiles sequential.
    const uint32_t linear = blockIdx.x + 64u * blockIdx.y;   // x fastest = dispatch order
    const uint32_t swz = (linear & 7u) * 4096u + (linear >> 3);
    const int r0 = (int)(swz & 63u) * 128;    // row tile (M fast axis)
    const int c0 = (int)(swz >> 6) * 128;     // column panel

    f32x4 acc[4][4];
#pragma unroll
    for (int i = 0; i < 4; ++i)
#pragma unroll
        for (int j = 0; j < 4; ++j) acc[i][j] = (f32x4){0.f, 0.f, 0.f, 0.f};

    const int lrow = lane >> 2, lcol = (lane & 3) * 8;   // staging: lane -> 16B slot
    const int frow = lane & 15, fk = (lane >> 4) * 8;    // MFMA fragment mapping

    // K_eff = 768 in 24 BK=32 chunks. Term order (AhBh, AlBh, AhBl) keeps the two
    // Bh sweeps adjacent so the second hits L2.
    auto stage = [&](int ch, int buf) {
        const int term = ch >> 3;
        const int d0 = (ch & 7) << 5;
        const _Float16* Asrc = (term == 1) ? Al : Ah;
        const _Float16* Bsrc = (term == 2) ? Bl : Bh;
        const _Float16* ga = Asrc + (size_t)(r0 + wid * 16 + lrow) * D_N + d0 + lcol;
        gload_lds16(ga,            &As[buf][wid * 16][0]);
        gload_lds16(ga + 64 * D_N, &As[buf][64 + wid * 16][0]);
        const _Float16* gb = Bsrc + (size_t)(c0 + wid * 16 + lrow) * D_N + d0 + lcol;
        gload_lds16(gb,            &Bs[buf][wid * 16][0]);
        gload_lds16(gb + 64 * D_N, &Bs[buf][64 + wid * 16][0]);
    };

    // prologue
    stage(0, 0);
    __syncthreads();   // drains vmcnt(0): chunk 0 resident

    int cur = 0;
    for (int ch = 0; ch < NCHUNK; ++ch) {
        if (ch + 1 < NCHUNK) stage(ch + 1, cur ^ 1);   // issue next-chunk loads FIRST

        half8 a[4], b[4];
#pragma unroll
        for (int mi = 0; mi < 4; ++mi)
            a[mi] = *reinterpret_cast<const half8*>(&As[cur][wr * 64 + mi * 16 + frow][fk]);
#pragma unroll
        for (int ni = 0; ni < 4; ++ni)
            b[ni] = *reinterpret_cast<const half8*>(&Bs[cur][wc * 64 + ni * 16 + frow][fk]);
#pragma unroll
        for (int mi = 0; mi < 4; ++mi)
#pragma unroll
            for (int ni = 0; ni < 4; ++ni)
                acc[mi][ni] = __builtin_amdgcn_mfma_f32_16x16x32_f16(a[mi], b[ni], acc[mi][ni], 0, 0, 0);

        __syncthreads();   // vmcnt(0) drain = next-chunk loads landed; flip
        cur ^= 1;
    }

    // epilogue: C/D layout col=lane&15, row=(lane>>4)*4+reg (m89-verified, dtype-independent)
    const int q = lane >> 4;
    const int cl = lane & 15;
    float cns[4];
#pragma unroll
    for (int ni = 0; ni < 4; ++ni) cns[ni] = cn[c0 + wc * 64 + ni * 16 + cl];

#pragma unroll
    for (int mi = 0; mi < 4; ++mi) {
#pragma unroll
        for (int reg = 0; reg < 4; ++reg) {
            const int row = r0 + wr * 64 + mi * 16 + q * 4 + reg;
            const float rv = rn[row];
            unsigned long long key = 0ull;
#pragma unroll
            for (int ni = 0; ni < 4; ++ni) {
                float v = acc[mi][ni][reg] * INV_SCALE / (rv * cns[ni] + EPS_);
                unsigned long long cand = pack_key(v, (uint32_t)(c0 + wc * 64 + ni * 16 + cl));
                key = cand > key ? cand : key;
            }
            // reduce across the 16 lanes sharing q (same rows, different cols)
#pragma unroll
            for (int m = 1; m <= 8; m <<= 1) {
                uint32_t lo = (uint32_t)key, hi = (uint32_t)(key >> 32);
                lo = __shfl_xor(lo, m);
                hi = __shfl_xor(hi, m);
                unsigned long long o = ((unsigned long long)hi << 32) | (unsigned long long)lo;
                key = o > key ? o : key;
            }
            if (cl == 0) atomicMax(&packed[row], key);
        }
    }
}

// ---------- f32 fallback (round-2 verified path, used only if ws too small) ----------

#define TM 128
#define TN 128
#define DK 32
#define LDT 132

__launch_bounds__(256) __global__
void fused_sim_argmax_kernel(const float* __restrict__ T, const float* __restrict__ W,
                             const float* __restrict__ rn, const float* __restrict__ cn,
                             unsigned long long* __restrict__ packed) {
    __shared__ __align__(16) float As[DK][LDT];
    __shared__ __align__(16) float Ws[DK][LDT];
    const int tid = threadIdx.x;
    const int tx = tid & 15, ty = tid >> 4;
    const int r0 = blockIdx.y * TM, c0 = blockIdx.x * TN;
    float acc[8][8] = {};
    for (int d0 = 0; d0 < D_N; d0 += DK) {
#pragma unroll
        for (int t = 0; t < 4; ++t) {
            int fidx = tid + t * 256;
            int r = fidx >> 3, dq = fidx & 7;
            float4 v = *reinterpret_cast<const float4*>(T + (size_t)(r0 + r) * D_N + d0 + dq * 4);
            As[dq * 4 + 0][r] = v.x; As[dq * 4 + 1][r] = v.y;
            As[dq * 4 + 2][r] = v.z; As[dq * 4 + 3][r] = v.w;
        }
#pragma unroll
        for (int t = 0; t < 4; ++t) {
            int fidx = tid + t * 256;
            int dd = fidx >> 5, c4 = fidx & 31;
            float4 v = *reinterpret_cast<const float4*>(W + (size_t)(d0 + dd) * K_N + c0 + c4 * 4);
            *reinterpret_cast<float4*>(&Ws[dd][c4 * 4]) = v;
        }
        __syncthreads();
#pragma unroll 8
        for (int dd = 0; dd < DK; ++dd) {
            float a[8], w[8];
            *reinterpret_cast<float4*>(&a[0]) = *reinterpret_cast<const float4*>(&As[dd][ty * 8]);
            *reinterpret_cast<float4*>(&a[4]) = *reinterpret_cast<const float4*>(&As[dd][ty * 8 + 4]);
            *reinterpret_cast<float4*>(&w[0]) = *reinterpret_cast<const float4*>(&Ws[dd][tx * 8]);
            *reinterpret_cast<float4*>(&w[4]) = *reinterpret_cast<const float4*>(&Ws[dd][tx * 8 + 4]);
#pragma unroll
            for (int i = 0; i < 8; ++i)
#pragma unroll
                for (int j = 0; j < 8; ++j) acc[i][j] = fmaf(a[i], w[j], acc[i][j]);
        }
        __syncthreads();
    }
    float rns[8], cns[8];
#pragma unroll
    for (int i = 0; i < 8; ++i) rns[i] = rn[r0 + ty * 8 + i];
#pragma unroll
    for (int j = 0; j < 8; ++j) cns[j] = cn[c0 + tx * 8 + j];
#pragma unroll
    for (int i = 0; i < 8; ++i) {
        unsigned long long key = 0ull;
#pragma unroll
        for (int j = 0; j < 8; ++j) {
            float v = acc[i][j] / (rns[i] * cns[j] + EPS_);
            unsigned long long cand = pack_key(v, (uint32_t)(c0 + tx * 8 + j));
            key = cand > key ? cand : key;
        }
#pragma unroll
        for (int m = 1; m <= 8; m <<= 1) {
            uint32_t lo = (uint32_t)key, hi = (uint32_t)(key >> 32);
            lo = __shfl_xor(lo, m); hi = __shfl_xor(hi, m);
            unsigned long long o = ((unsigned long long)hi << 32) | (unsigned long long)lo;
            key = o > key ? o : key;
        }
        if (tx == 0) atomicMax(&packed[r0 + ty * 8 + i], key);
    }
}

// ---------- launch ----------

extern "C" void kernel_launch(void* const* d_in, const int* in_sizes, int n_in,
                              void* d_out, int out_size, void* d_ws, size_t ws_size,
                              hipStream_t stream) {
    const float* T = (const float*)d_in[0];   // [B, D]
    const float* W = (const float*)d_in[1];   // [D, K]
    float* out = (float*)d_out;

    // ws layout (fp16 path): Bh | Bl | Ah | Al | cn | rn | packed
    const size_t BH_OFF = 0;
    const size_t BL_OFF = BH_OFF + (size_t)K_N * D_N * 2;
    const size_t AH_OFF = BL_OFF + (size_t)K_N * D_N * 2;
    const size_t AL_OFF = AH_OFF + (size_t)B_N * D_N * 2;
    const size_t CN_OFF = AL_OFF + (size_t)B_N * D_N * 2;
    const size_t RN_OFF = CN_OFF + (size_t)K_N * 4;
    const size_t PK_OFF = RN_OFF + (size_t)B_N * 4;
    const size_t NEED = PK_OFF + (size_t)B_N * 8;

    char* ws = (char*)d_ws;

    if (ws_size >= NEED) {
        _Float16* Bh = (_Float16*)(ws + BH_OFF);
        _Float16* Bl = (_Float16*)(ws + BL_OFF);
        _Float16* Ah = (_Float16*)(ws + AH_OFF);
        _Float16* Al = (_Float16*)(ws + AL_OFF);
        float* cn = (float*)(ws + CN_OFF);
        float* rn = (float*)(ws + RN_OFF);
        unsigned long long* packed = (unsigned long long*)(ws + PK_OFF);

        colnorm_init_kernel<<<K_N / 256, 256, 0, stream>>>(W, cn, packed);
        rownorm_kernel<<<B_N / 4, 256, 0, stream>>>(T, rn);
        convT_kernel<<<B_N * D_N / 4 / 256, 256, 0, stream>>>(T, Ah, Al);
        dim3 gw(K_N / 64, D_N / 64);
        convW_kernel<<<gw, 256, 0, stream>>>(W, Bh, Bl);

        dim3 grid(64, 512);   // x = row-tiles (M fast), y = column-panels
        fused_mfma_kernel<<<grid, 256, 0, stream>>>(Ah, Al, Bh, Bl, rn, cn, packed);

        gather_kernel<<<B_N, 256, 0, stream>>>(W, packed, out);
    } else {
        // f32 fallback (round-2 verified)
        float* cn = (float*)ws;
        float* rn = cn + K_N;
        unsigned long long* packed = (unsigned long long*)(rn + B_N);
        colnorm_init_kernel<<<K_N / 256, 256, 0, stream>>>(W, cn, packed);
        rownorm_kernel<<<B_N / 4, 256, 0, stream>>>(T, rn);
        dim3 grid(K_N / TN, B_N / TM);
        fused_sim_argmax_kernel<<<grid, 256, 0, stream>>>(T, W, rn, cn, packed);
        gather_kernel<<<B_N, 256, 0, stream>>>(W, packed, out);
    }
}

// Round 7
// 1502.430 us; speedup vs baseline: 2.3913x; 1.0275x over previous
//
#include <hip/hip_runtime.h>
#include <stdint.h>

#define B_N 8192
#define D_N 256
#define K_N 65536
#define EPS_ 1e-7f

#define T_SCALE 256.0f
#define W_SCALE 1024.0f
#define INV_SCALE (1.0f / 262144.0f)   // 1 / (256*1024), exact power of 2

typedef _Float16 half8 __attribute__((ext_vector_type(8)));
typedef _Float16 half4 __attribute__((ext_vector_type(4)));
typedef float f32x4 __attribute__((ext_vector_type(4)));

// monotone float->uint mapping; pack value in high 32, ~idx in low 32 so that
// u64 max == (max value, then smallest index) — matches numpy argmax tie-break.
__device__ __forceinline__ unsigned long long pack_key(float v, uint32_t k) {
    uint32_t u = __float_as_uint(v);
    u = (u & 0x80000000u) ? ~u : (u | 0x80000000u);
    return ((unsigned long long)u << 32) | (unsigned long long)(~k);
}

// ---------- shared prep kernels (operate on ORIGINAL data) ----------

__global__ void colnorm_init_kernel(const float* __restrict__ W, float* __restrict__ cn,
                                    unsigned long long* __restrict__ packed) {
    int k = blockIdx.x * blockDim.x + threadIdx.x;
    float s = 0.f;
#pragma unroll 8
    for (int d = 0; d < D_N; ++d) {
        float w = W[(size_t)d * K_N + k];
        s = fmaf(w, w, s);
    }
    cn[k] = sqrtf(s);
    if (k < B_N) packed[k] = 0ull;
}

__global__ void rownorm_kernel(const float* __restrict__ T, float* __restrict__ rn) {
    int row = blockIdx.x * 4 + (threadIdx.x >> 6);
    int lane = threadIdx.x & 63;
    float4 v = reinterpret_cast<const float4*>(T + (size_t)row * D_N)[lane];
    float s = v.x * v.x + v.y * v.y + v.z * v.z + v.w * v.w;
#pragma unroll
    for (int off = 32; off > 0; off >>= 1) s += __shfl_down(s, off);
    if (lane == 0) rn[row] = sqrtf(s);
}

__global__ void gather_kernel(const float* __restrict__ W,
                              const unsigned long long* __restrict__ packed,
                              float* __restrict__ out) {
    int b = blockIdx.x;
    int d = threadIdx.x;
    uint32_t idx = ~(uint32_t)(packed[b]);
    out[(size_t)b * D_N + d] = W[(size_t)d * K_N + idx];
}

// ---------- fp16 split conversion ----------

__global__ void convT_kernel(const float* __restrict__ T,
                             _Float16* __restrict__ Ah, _Float16* __restrict__ Al) {
    int i = blockIdx.x * 256 + threadIdx.x;       // float4 index
    float4 v = reinterpret_cast<const float4*>(T)[i];
    float x[4] = {v.x, v.y, v.z, v.w};
    half4 hv, lv;
#pragma unroll
    for (int j = 0; j < 4; ++j) {
        float s = x[j] * T_SCALE;
        _Float16 h = (_Float16)s;
        hv[j] = h;
        lv[j] = (_Float16)(s - (float)h);
    }
    reinterpret_cast<half4*>(Ah)[i] = hv;
    reinterpret_cast<half4*>(Al)[i] = lv;
}

// W [256][65536] f32 -> Bh, Bl [65536][256] fp16 TRANSPOSED (scaled by 1024)
__global__ void convW_kernel(const float* __restrict__ W,
                             _Float16* __restrict__ Bh, _Float16* __restrict__ Bl) {
    __shared__ _Float16 Lh[64][66], Ll[64][66];   // [d_local][k_local], padded
    int k0 = blockIdx.x * 64, d0 = blockIdx.y * 64;
    int t = threadIdx.x;
#pragma unroll
    for (int i = 0; i < 16; ++i) {
        int flat = i * 256 + t;                   // 0..4095
        int dl = flat >> 6, kl = flat & 63;
        float x = W[(size_t)(d0 + dl) * K_N + k0 + kl] * W_SCALE;
        _Float16 h = (_Float16)x;
        Lh[dl][kl] = h;
        Ll[dl][kl] = (_Float16)(x - (float)h);
    }
    __syncthreads();
#pragma unroll
    for (int j = 0; j < 2; ++j) {
        int flat = j * 256 + t;                   // 0..511
        int kr = flat >> 3, seg = flat & 7;
        half8 vh, vl;
#pragma unroll
        for (int e = 0; e < 8; ++e) {
            vh[e] = Lh[seg * 8 + e][kr];
            vl[e] = Ll[seg * 8 + e][kr];
        }
        *reinterpret_cast<half8*>(Bh + (size_t)(k0 + kr) * D_N + d0 + seg * 8) = vh;
        *reinterpret_cast<half8*>(Bl + (size_t)(k0 + kr) * D_N + d0 + seg * 8) = vl;
    }
}

// ---------- fused MFMA GEMM + argmax ----------
// 128^2 tile, BK=32, fully-unrolled K_eff=768, 3-buffer depth-2 pipeline with
// counted vmcnt (T3+T4), XOR bank-swizzled LDS (both-sides via pre-swizzled
// global source, rule #21), XCD-panel swizzle.

__device__ __forceinline__ void gload_lds16(const _Float16* g, _Float16* l) {
    __builtin_amdgcn_global_load_lds((const __attribute__((address_space(1))) unsigned int*)g,
                                     (__attribute__((address_space(3))) unsigned int*)l, 16, 0, 0);
}

#define NCHUNK 24

__launch_bounds__(256, 3) __global__
void fused_mfma_kernel(const _Float16* __restrict__ Ah, const _Float16* __restrict__ Al,
                       const _Float16* __restrict__ Bh, const _Float16* __restrict__ Bl,
                       const float* __restrict__ rn, const float* __restrict__ cn,
                       unsigned long long* __restrict__ packed) {
    // 3 buffers x 128 rows x 32 k fp16 = 24 KB each array, 48 KB total
    __shared__ _Float16 sA[3 * 128 * 32];
    __shared__ _Float16 sB[3 * 128 * 32];

    const int tid = threadIdx.x;
    const int lane = tid & 63, wid = tid >> 6;
    const int wr = wid >> 1, wc = wid & 1;           // wave -> 64x64 quadrant

    // bijective XCD swizzle (m204 class): 32768 blocks, 8 XCDs, 4096 blocks/XCD.
    const uint32_t linear = blockIdx.x + 64u * blockIdx.y;
    const uint32_t swz = (linear & 7u) * 4096u + (linear >> 3);
    const int r0 = (int)(swz & 63u) * 128;    // row tile (M fast axis)
    const int c0 = (int)(swz >> 6) * 128;     // column panel

    f32x4 acc[4][4];
#pragma unroll
    for (int i = 0; i < 4; ++i)
#pragma unroll
        for (int j = 0; j < 4; ++j) acc[i][j] = (f32x4){0.f, 0.f, 0.f, 0.f};

    // ---- staging lane mapping (write side of the XOR swizzle) ----
    // physical 16B slot l holds logical chunk (l&3) ^ ((l>>3)&3) of row l>>2
    const int srow = lane >> 2;
    const int scol = ((lane & 3) ^ ((lane >> 3) & 3)) * 8;
    const _Float16* pAh = Ah + (size_t)(r0 + wid * 16 + srow) * D_N + scol;
    const _Float16* pAl = Al + (size_t)(r0 + wid * 16 + srow) * D_N + scol;
    const _Float16* pBh = Bh + (size_t)(c0 + wid * 16 + srow) * D_N + scol;
    const _Float16* pBl = Bl + (size_t)(c0 + wid * 16 + srow) * D_N + scol;
    _Float16* ldsA = sA + wid * 512;   // wave-uniform base; +b*4096, +2048 for 2nd row block
    _Float16* ldsB = sB + wid * 512;

    // ---- fragment read mapping (read side of the XOR swizzle) ----
    // logical chunk lane>>4 of row frow lives at physical chunk (lane>>4)^((frow>>1)&3)
    const int frow = lane & 15;
    const int fkp = ((lane >> 4) ^ ((frow >> 1) & 3)) * 8;
    const _Float16* rA = sA + (wr * 64 + frow) * 32 + fkp;   // +b*4096 +mi*512
    const _Float16* rB = sB + (wc * 64 + frow) * 32 + fkp;

    // term t: 0 = Ah*Bh, 1 = Al*Bh, 2 = Ah*Bl (l*l dropped, ~2^-24 rel)
#define STAGE(ch, b) {                                                        \
        const _Float16* pa = (((ch) >> 3) == 1) ? pAl : pAh;                  \
        const _Float16* pb = (((ch) >> 3) == 2) ? pBl : pBh;                  \
        const int dd = ((ch) & 7) * 32;                                       \
        gload_lds16(pa + dd,             ldsA + (b) * 4096);                  \
        gload_lds16(pa + dd + 64 * D_N,  ldsA + (b) * 4096 + 2048);           \
        gload_lds16(pb + dd,             ldsB + (b) * 4096);                  \
        gload_lds16(pb + dd + 64 * D_N,  ldsB + (b) * 4096 + 2048);           \
    }

    // prologue: 2 chunks in flight (8 loads)
    STAGE(0, 0);
    STAGE(1, 1);

#pragma unroll
    for (int ch = 0; ch < NCHUNK; ++ch) {
        const int b = ch % 3;
        if (ch + 2 < NCHUNK) STAGE(ch + 2, (ch + 2) % 3);   // 12 loads in flight

        // counted wait: chunk ch's 4 loads retired; up to 8 (ch+1, ch+2) stay in flight
        if (ch < NCHUNK - 2)       asm volatile("s_waitcnt vmcnt(8)" ::: "memory");
        else if (ch == NCHUNK - 2) asm volatile("s_waitcnt vmcnt(4)" ::: "memory");
        else                       asm volatile("s_waitcnt vmcnt(0)" ::: "memory");
        __builtin_amdgcn_s_barrier();          // all waves: chunk ch resident
        __builtin_amdgcn_sched_barrier(0);     // pin reads below the barrier

        const _Float16* rAb = rA + b * 4096;
        const _Float16* rBb = rB + b * 4096;
        half8 a[4], bf[4];
#pragma unroll
        for (int mi = 0; mi < 4; ++mi)
            a[mi] = *reinterpret_cast<const half8*>(rAb + mi * 512);
#pragma unroll
        for (int ni = 0; ni < 4; ++ni)
            bf[ni] = *reinterpret_cast<const half8*>(rBb + ni * 512);
#pragma unroll
        for (int mi = 0; mi < 4; ++mi)
#pragma unroll
            for (int ni = 0; ni < 4; ++ni)
                acc[mi][ni] = __builtin_amdgcn_mfma_f32_16x16x32_f16(a[mi], bf[ni], acc[mi][ni], 0, 0, 0);

        __builtin_amdgcn_sched_barrier(0);     // keep reads/MFMA inside the phase
        __builtin_amdgcn_s_barrier();          // chunk ch fully consumed -> buffer b reusable
    }
#undef STAGE

    // epilogue: C/D layout col=lane&15, row=(lane>>4)*4+reg (m89-verified)
    const int q = lane >> 4;
    const int cl = lane & 15;
    float cns[4];
#pragma unroll
    for (int ni = 0; ni < 4; ++ni) cns[ni] = cn[c0 + wc * 64 + ni * 16 + cl];

#pragma unroll
    for (int mi = 0; mi < 4; ++mi) {
#pragma unroll
        for (int reg = 0; reg < 4; ++reg) {
            const int row = r0 + wr * 64 + mi * 16 + q * 4 + reg;
            const float rv = rn[row];
            unsigned long long key = 0ull;
#pragma unroll
            for (int ni = 0; ni < 4; ++ni) {
                float v = acc[mi][ni][reg] * INV_SCALE / (rv * cns[ni] + EPS_);
                unsigned long long cand = pack_key(v, (uint32_t)(c0 + wc * 64 + ni * 16 + cl));
                key = cand > key ? cand : key;
            }
#pragma unroll
            for (int m = 1; m <= 8; m <<= 1) {
                uint32_t lo = (uint32_t)key, hi = (uint32_t)(key >> 32);
                lo = __shfl_xor(lo, m);
                hi = __shfl_xor(hi, m);
                unsigned long long o = ((unsigned long long)hi << 32) | (unsigned long long)lo;
                key = o > key ? o : key;
            }
            if (cl == 0) atomicMax(&packed[row], key);
        }
    }
}

// ---------- f32 fallback (round-2 verified path, used only if ws too small) ----------

#define TM 128
#define TN 128
#define DK 32
#define LDT 132

__launch_bounds__(256) __global__
void fused_sim_argmax_kernel(const float* __restrict__ T, const float* __restrict__ W,
                             const float* __restrict__ rn, const float* __restrict__ cn,
                             unsigned long long* __restrict__ packed) {
    __shared__ __align__(16) float As[DK][LDT];
    __shared__ __align__(16) float Ws[DK][LDT];
    const int tid = threadIdx.x;
    const int tx = tid & 15, ty = tid >> 4;
    const int r0 = blockIdx.y * TM, c0 = blockIdx.x * TN;
    float acc[8][8] = {};
    for (int d0 = 0; d0 < D_N; d0 += DK) {
#pragma unroll
        for (int t = 0; t < 4; ++t) {
            int fidx = tid + t * 256;
            int r = fidx >> 3, dq = fidx & 7;
            float4 v = *reinterpret_cast<const float4*>(T + (size_t)(r0 + r) * D_N + d0 + dq * 4);
            As[dq * 4 + 0][r] = v.x; As[dq * 4 + 1][r] = v.y;
            As[dq * 4 + 2][r] = v.z; As[dq * 4 + 3][r] = v.w;
        }
#pragma unroll
        for (int t = 0; t < 4; ++t) {
            int fidx = tid + t * 256;
            int dd = fidx >> 5, c4 = fidx & 31;
            float4 v = *reinterpret_cast<const float4*>(W + (size_t)(d0 + dd) * K_N + c0 + c4 * 4);
            *reinterpret_cast<float4*>(&Ws[dd][c4 * 4]) = v;
        }
        __syncthreads();
#pragma unroll 8
        for (int dd = 0; dd < DK; ++dd) {
            float a[8], w[8];
            *reinterpret_cast<float4*>(&a[0]) = *reinterpret_cast<const float4*>(&As[dd][ty * 8]);
            *reinterpret_cast<float4*>(&a[4]) = *reinterpret_cast<const float4*>(&As[dd][ty * 8 + 4]);
            *reinterpret_cast<float4*>(&w[0]) = *reinterpret_cast<const float4*>(&Ws[dd][tx * 8]);
            *reinterpret_cast<float4*>(&w[4]) = *reinterpret_cast<const float4*>(&Ws[dd][tx * 8 + 4]);
#pragma unroll
            for (int i = 0; i < 8; ++i)
#pragma unroll
                for (int j = 0; j < 8; ++j) acc[i][j] = fmaf(a[i], w[j], acc[i][j]);
        }
        __syncthreads();
    }
    float rns[8], cns[8];
#pragma unroll
    for (int i = 0; i < 8; ++i) rns[i] = rn[r0 + ty * 8 + i];
#pragma unroll
    for (int j = 0; j < 8; ++j) cns[j] = cn[c0 + tx * 8 + j];
#pragma unroll
    for (int i = 0; i < 8; ++i) {
        unsigned long long key = 0ull;
#pragma unroll
        for (int j = 0; j < 8; ++j) {
            float v = acc[i][j] / (rns[i] * cns[j] + EPS_);
            unsigned long long cand = pack_key(v, (uint32_t)(c0 + tx * 8 + j));
            key = cand > key ? cand : key;
        }
#pragma unroll
        for (int m = 1; m <= 8; m <<= 1) {
            uint32_t lo = (uint32_t)key, hi = (uint32_t)(key >> 32);
            lo = __shfl_xor(lo, m); hi = __shfl_xor(hi, m);
            unsigned long long o = ((unsigned long long)hi << 32) | (unsigned long long)lo;
            key = o > key ? o : key;
        }
        if (tx == 0) atomicMax(&packed[r0 + ty * 8 + i], key);
    }
}

// ---------- launch ----------

extern "C" void kernel_launch(void* const* d_in, const int* in_sizes, int n_in,
                              void* d_out, int out_size, void* d_ws, size_t ws_size,
                              hipStream_t stream) {
    const float* T = (const float*)d_in[0];   // [B, D]
    const float* W = (const float*)d_in[1];   // [D, K]
    float* out = (float*)d_out;

    // ws layout (fp16 path): Bh | Bl | Ah | Al | cn | rn | packed
    const size_t BH_OFF = 0;
    const size_t BL_OFF = BH_OFF + (size_t)K_N * D_N * 2;
    const size_t AH_OFF = BL_OFF + (size_t)K_N * D_N * 2;
    const size_t AL_OFF = AH_OFF + (size_t)B_N * D_N * 2;
    const size_t CN_OFF = AL_OFF + (size_t)B_N * D_N * 2;
    const size_t RN_OFF = CN_OFF + (size_t)K_N * 4;
    const size_t PK_OFF = RN_OFF + (size_t)B_N * 4;
    const size_t NEED = PK_OFF + (size_t)B_N * 8;

    char* ws = (char*)d_ws;

    if (ws_size >= NEED) {
        _Float16* Bh = (_Float16*)(ws + BH_OFF);
        _Float16* Bl = (_Float16*)(ws + BL_OFF);
        _Float16* Ah = (_Float16*)(ws + AH_OFF);
        _Float16* Al = (_Float16*)(ws + AL_OFF);
        float* cn = (float*)(ws + CN_OFF);
        float* rn = (float*)(ws + RN_OFF);
        unsigned long long* packed = (unsigned long long*)(ws + PK_OFF);

        colnorm_init_kernel<<<K_N / 256, 256, 0, stream>>>(W, cn, packed);
        rownorm_kernel<<<B_N / 4, 256, 0, stream>>>(T, rn);
        convT_kernel<<<B_N * D_N / 4 / 256, 256, 0, stream>>>(T, Ah, Al);
        dim3 gw(K_N / 64, D_N / 64);
        convW_kernel<<<gw, 256, 0, stream>>>(W, Bh, Bl);

        dim3 grid(64, 512);   // x = row-tiles (M fast), y = column-panels
        fused_mfma_kernel<<<grid, 256, 0, stream>>>(Ah, Al, Bh, Bl, rn, cn, packed);

        gather_kernel<<<B_N, 256, 0, stream>>>(W, packed, out);
    } else {
        // f32 fallback (round-2 verified)
        float* cn = (float*)ws;
        float* rn = cn + K_N;
        unsigned long long* packed = (unsigned long long*)(rn + B_N);
        colnorm_init_kernel<<<K_N / 256, 256, 0, stream>>>(W, cn, packed);
        rownorm_kernel<<<B_N / 4, 256, 0, stream>>>(T, rn);
        dim3 grid(K_N / TN, B_N / TM);
        fused_sim_argmax_kernel<<<grid, 256, 0, stream>>>(T, W, rn, cn, packed);
        gather_kernel<<<B_N, 256, 0, stream>>>(W, packed, out);
    }
}